// Round 9
// baseline (740.265 us; speedup 1.0000x reference)
//
#include <hip/hip_runtime.h>
#include <hip/hip_bf16.h>

typedef __hip_bfloat16 bf16;
typedef __attribute__((ext_vector_type(8))) short bf16x8;
typedef __attribute__((ext_vector_type(4))) float f32x4;

#define MFMA16(a, b, c) __builtin_amdgcn_mfma_f32_16x16x32_bf16(a, b, c, 0, 0, 0)

// Problem constants (B=1)
#define HH 256
#define WW 256
#define NHEADS 8
#define NROWS 65536

// ws layout:
//   R0 @ 0          (67108864): width Ow (w-major) -- written by fused width kernel
//   R1 @ 67108864   : unused
//   R2 @ 134217728  (67108864): Oh (h-major), written by k_h_pv_f
//   R3 @ 201326592  (2097152):  Wt (384K) @+0 | P bf16 (1M) @+393216 | Wo_w/Wo_h @+1441792
//   d_out doubles as split-K dots scratch dp (8 x 2MB exact) before k_outproj overwrites it.
//
// LESSONS:
//   (R4/R5) __launch_bounds__(256, N) caps VGPRs at ~256/N on this toolchain --
//     (256,2)->128 ok; (256,3)->84 spilled acc to scratch (1.6 GB/dispatch). Never N>=3
//     for register-heavy kernels.
//   (R6) quarter K/V tiles: 2x barriers + 2x Wt re-reads, occupancy unchanged -> 126->154us.
//     R3 half-tile structure is the proven best width kernel.
//   (R2/R3/R7) the only >10% levers on this pipeline are DELETED BYTES: fusing the QKV
//     projection into its consumer (recompute from cache-resident x) beats any store/
//     load pattern tuning of the ws round trip.
//   (R7/R8) k_dots_f residency is pinned at ~4 blocks/CU (43% occ) regardless of grid
//     size -- rc=16 was neutral-negative. The limiter is the per-iteration serial
//     {proj -> barrier -> dots -> barrier} chain => software-pipeline it (R9).
//
// MFMA fragment conventions (verified m89/m91/m120):
//   A-frag: lane l holds A[m = l&15][k = (l>>4)*8 + t], t=0..7
//   B-frag: lane l holds B[n = l&15][k = (l>>4)*8 + t]
//   C/D   : lane l, reg r -> (col = l&15, row = (l>>4)*4 + r)
//   D[m][n] = sum_k A[m][k]*B[n][k]

__device__ __forceinline__ bf16x8 cvt8(const float* f) {
  bf16x8 r;
  bf16* h = (bf16*)&r;
#pragma unroll
  for (int i = 0; i < 8; i++) h[i] = __float2bfloat16(f[i]);
  return r;
}

// ---------------------------------------------------------------- Wq|Wkv transpose -> bf16 [1536][64]
__global__ void __launch_bounds__(256) k_wt1(const float* __restrict__ Wq,
                                             const float* __restrict__ Wkv,
                                             bf16* __restrict__ Wt) {
  const int idx = blockIdx.x * 256 + threadIdx.x;  // [0, 98304)
  const int k = idx / 1536, c = idx - k * 1536;
  const float val = (c < 512) ? Wq[k * 512 + c] : Wkv[k * 1024 + (c - 512)];
  Wt[(size_t)c * 64 + k] = __float2bfloat16(val);
}

// ---------------------------------------------------------------- Wout transpose -> bf16 [64][512]
__global__ void __launch_bounds__(256) k_wo(const float* __restrict__ Wout_w,
                                            const float* __restrict__ Wout_h,
                                            bf16* __restrict__ Wo_w,
                                            bf16* __restrict__ Wo_h) {
  int idx = blockIdx.x * 256 + threadIdx.x;  // [0, 65536)
  const float* W = Wout_w;
  bf16* dst = Wo_w;
  if (idx >= 32768) { idx -= 32768; W = Wout_h; dst = Wo_h; }
  const int c = idx >> 9, d = idx & 511;
  dst[idx] = __float2bfloat16(W[d * 64 + c]);  // Wo[c][d] = Wout[d][c]
}

// ---------------------------------------------------------------- FUSED width QKV + attention
// R3-proven structure (126 us): block (w, head), 4 waves, reads x directly.
// LDS 65536 (2 blocks/CU):
//   Qs [256][64] granule-XOR-swizzled @0      (32 KB) -> Ps (4x5 KB) overlays after qf load
//   Ks [128][64] granule-XOR-swizzled @32768  (16 KB) -- one 128-row HALF at a time
//   Vt [64 d][128 j] granule-XOR-swizzled @49152 (16 KB)
// Swizzle: element (row, c) at row*64 + (((c>>3) ^ (row&7))<<3) + (c&7).
__global__ void __launch_bounds__(256, 2)
k_width_fused(const float* __restrict__ x, const bf16* __restrict__ Wt,
              bf16* __restrict__ Ow) {
  __shared__ __align__(16) char smem[65536];
  bf16* Qs = (bf16*)smem;
  bf16* Ks = (bf16*)(smem + 32768);
  bf16* Vt = (bf16*)(smem + 49152);
  const int w = blockIdx.x, head = blockIdx.y;
  const int tid = threadIdx.x, lane = tid & 63, wv = tid >> 6;
  bf16* Ps = (bf16*)(smem + wv * 5120);  // overlays Qs (dead after qf load)
  const int m16 = lane & 15, kq = lane >> 4;
  const int i0 = wv * 64;

  // ---- Q phase: this wave's 64 rows (i = h), all 64 head-cols ----
  bf16x8 af[4][2];
#pragma unroll
  for (int mt = 0; mt < 4; mt++) {
    const float* xr = x + ((size_t)((i0 + mt * 16 + m16) * 256 + w)) * 64;
    float xf[8];
    *(float4*)&xf[0] = *(const float4*)(xr + kq * 8);
    *(float4*)&xf[4] = *(const float4*)(xr + kq * 8 + 4);
    af[mt][0] = cvt8(xf);
    *(float4*)&xf[0] = *(const float4*)(xr + 32 + kq * 8);
    *(float4*)&xf[4] = *(const float4*)(xr + 32 + kq * 8 + 4);
    af[mt][1] = cvt8(xf);
  }
#pragma unroll
  for (int nt = 0; nt < 4; nt++) {
    const bf16* wp = Wt + (size_t)(head * 64 + nt * 16 + m16) * 64 + kq * 8;
    const bf16x8 w0 = *(const bf16x8*)wp;
    const bf16x8 w1 = *(const bf16x8*)(wp + 32);
#pragma unroll
    for (int mt = 0; mt < 4; mt++) {
      f32x4 a = (f32x4){0.f, 0.f, 0.f, 0.f};
      a = MFMA16(af[mt][0], w0, a);
      a = MFMA16(af[mt][1], w1, a);
#pragma unroll
      for (int r = 0; r < 4; r++) {
        const int i = i0 + mt * 16 + kq * 4 + r;
        const int d = nt * 16 + m16;
        Qs[i * 64 + (((d >> 3) ^ (i & 7)) << 3) + (d & 7)] = __float2bfloat16(a[r]);
      }
    }
  }
  __syncthreads();
  // qf A-frags from own rows (swizzled read, conflict-free)
  bf16x8 qf[4][2];
#pragma unroll
  for (int it = 0; it < 4; it++)
#pragma unroll
    for (int ks = 0; ks < 2; ks++)
      qf[it][ks] = *(const bf16x8*)&Qs[(i0 + it * 16 + m16) * 64 +
                                       (((ks * 4 + kq) ^ (m16 & 7)) << 3)];

  f32x4 acc[4][4];
#pragma unroll
  for (int a = 0; a < 4; a++)
#pragma unroll
    for (int b = 0; b < 4; b++) acc[a][b] = (f32x4){0.f, 0.f, 0.f, 0.f};
  float rsum[4][4];
#pragma unroll
  for (int a = 0; a < 4; a++)
#pragma unroll
    for (int r = 0; r < 4; r++) rsum[a][r] = 0.f;

#pragma unroll 1
  for (int half = 0; half < 2; half++) {
    if (half) __syncthreads();  // all reads of prior half's Ks/Vt done
    // ---- K/V phase: this wave computes 32 rows (local j = wv*32..+32) of this half ----
    bf16x8 afk[2][2];
#pragma unroll
    for (int mt = 0; mt < 2; mt++) {
      const int jrow = half * 128 + wv * 32 + mt * 16 + m16;  // global j (= h)
      const float* xr = x + ((size_t)(jrow * 256 + w)) * 64;
      float xf[8];
      *(float4*)&xf[0] = *(const float4*)(xr + kq * 8);
      *(float4*)&xf[4] = *(const float4*)(xr + kq * 8 + 4);
      afk[mt][0] = cvt8(xf);
      *(float4*)&xf[0] = *(const float4*)(xr + 32 + kq * 8);
      *(float4*)&xf[4] = *(const float4*)(xr + 32 + kq * 8 + 4);
      afk[mt][1] = cvt8(xf);
    }
#pragma unroll
    for (int nt = 0; nt < 4; nt++) {
      const int d = nt * 16 + m16;
      {  // K -> Ks
        const bf16* wp = Wt + (size_t)(512 + head * 64 + d) * 64 + kq * 8;
        const bf16x8 w0 = *(const bf16x8*)wp;
        const bf16x8 w1 = *(const bf16x8*)(wp + 32);
#pragma unroll
        for (int mt = 0; mt < 2; mt++) {
          f32x4 a = (f32x4){0.f, 0.f, 0.f, 0.f};
          a = MFMA16(afk[mt][0], w0, a);
          a = MFMA16(afk[mt][1], w1, a);
#pragma unroll
          for (int r = 0; r < 4; r++) {
            const int jl = wv * 32 + mt * 16 + kq * 4 + r;  // local row in half
            Ks[jl * 64 + (((d >> 3) ^ (jl & 7)) << 3) + (d & 7)] = __float2bfloat16(a[r]);
          }
        }
      }
      {  // V -> Vt (transposed), 4 consecutive j packed as 8 B
        const bf16* wp = Wt + (size_t)(1024 + head * 64 + d) * 64 + kq * 8;
        const bf16x8 w0 = *(const bf16x8*)wp;
        const bf16x8 w1 = *(const bf16x8*)(wp + 32);
#pragma unroll
        for (int mt = 0; mt < 2; mt++) {
          f32x4 a = (f32x4){0.f, 0.f, 0.f, 0.f};
          a = MFMA16(afk[mt][0], w0, a);
          a = MFMA16(afk[mt][1], w1, a);
          const int jb = wv * 32 + mt * 16 + kq * 4;  // local j base (r=0..3)
          bf16 tmp[4];
#pragma unroll
          for (int r = 0; r < 4; r++) tmp[r] = __float2bfloat16(a[r]);
          *(uint2*)&Vt[d * 128 + (((jb >> 3) ^ (d & 7)) << 3) + (jb & 7)] =
              *(const uint2*)tmp;
        }
      }
    }
    __syncthreads();
    // ---- attention over this half's 128 j ----
#pragma unroll 1
    for (int jcl = 0; jcl < 4; jcl++) {
      bf16x8 kf[2][2];
#pragma unroll
      for (int jt = 0; jt < 2; jt++) {
        const int j = jcl * 32 + jt * 16 + m16;  // local row in half
#pragma unroll
        for (int ks = 0; ks < 2; ks++)
          kf[jt][ks] = *(const bf16x8*)&Ks[j * 64 + (((ks * 4 + kq) ^ (j & 7)) << 3)];
      }
#pragma unroll
      for (int it = 0; it < 4; it++)
#pragma unroll
        for (int jt = 0; jt < 2; jt++) {
          f32x4 s = (f32x4){0.f, 0.f, 0.f, 0.f};
          s = MFMA16(qf[it][0], kf[jt][0], s);
          s = MFMA16(qf[it][1], kf[jt][1], s);
#pragma unroll
          for (int r = 0; r < 4; r++) {
            float p = __expf(s[r] * 0.125f);
            rsum[it][r] += p;
            Ps[(it * 16 + kq * 4 + r) * 40 + jt * 16 + m16] = __float2bfloat16(p);
          }
        }
      bf16x8 pf[4], vf[4];
#pragma unroll
      for (int it = 0; it < 4; it++)
        pf[it] = *(const bf16x8*)&Ps[(it * 16 + m16) * 40 + kq * 8];
#pragma unroll
      for (int dt = 0; dt < 4; dt++)
        vf[dt] = *(const bf16x8*)&Vt[(dt * 16 + m16) * 128 +
                                     (((jcl * 4 + kq) ^ (m16 & 7)) << 3)];
#pragma unroll
      for (int it = 0; it < 4; it++)
#pragma unroll
        for (int dt = 0; dt < 4; dt++) acc[it][dt] = MFMA16(pf[it], vf[dt], acc[it][dt]);
    }
  }

#pragma unroll
  for (int it = 0; it < 4; it++)
#pragma unroll
    for (int r = 0; r < 4; r++) {
      float s = rsum[it][r];
      s += __shfl_xor(s, 1); s += __shfl_xor(s, 2);
      s += __shfl_xor(s, 4); s += __shfl_xor(s, 8);
      rsum[it][r] = 1.f / s;
    }
#pragma unroll
  for (int it = 0; it < 4; it++)
#pragma unroll
    for (int dt = 0; dt < 4; dt++)
#pragma unroll
      for (int r = 0; r < 4; r++) {
        const int i = i0 + it * 16 + kq * 4 + r;  // = h
        Ow[((size_t)(w * 256 + i)) * 512 + head * 64 + dt * 16 + m16] =
            __float2bfloat16(acc[it][dt][r] * rsum[it][r]);
      }
}

// ---------------------------------------------------------------- FUSED height tied dots, PIPELINED
// On-the-fly Q/K projection from x, double-buffered: iteration rr projects rr+1 into
// buf^1 while the dots MFMAs consume buf -> ONE barrier per iteration (was 2), and the
// proj x-load latency hides under the dots MFMAs. grid (16 tiles, 8 heads, 8 rc).
// LDS 2 x 18432 = 36864 B -> 4 blocks/CU (matches observed residency cap).
__global__ void __launch_bounds__(256)
k_dots_f(const float* __restrict__ x, const bf16* __restrict__ Wt, float* __restrict__ dp) {
  __shared__ __align__(16) bf16 Qs[2][64 * 72];
  __shared__ __align__(16) bf16 Ks[2][64 * 72];
  const int tile = blockIdx.x, head = blockIdx.y, rc = blockIdx.z;
  const int i0 = (tile >> 2) * 64, j0 = (tile & 3) * 64;
  const int tid = threadIdx.x, lane = tid & 63, wv = tid >> 6;
  const int m16 = lane & 15, kq = lane >> 4;
  float* slice = dp + (size_t)rc * 524288 + (size_t)head * 65536;

  const bf16* WtQ = Wt + (size_t)(head * 64) * 64 + kq * 8;
  const bf16* WtK = Wt + (size_t)(512 + head * 64) * 64 + kq * 8;

  f32x4 acc[4];
#pragma unroll
  for (int b = 0; b < 4; b++) acc[b] = (f32x4){0.f, 0.f, 0.f, 0.f};

  const int lrow = wv * 16 + kq * 4;

  // project q/k rows of iteration rr into buffer b
  auto proj = [&](int rr, int b) {
    const int rbase = (rc * 32 + rr) * 256;
    const float* xr = x + (size_t)(rbase + i0 + wv * 16 + m16) * 64;
    float xf[8];
    bf16x8 qa0, qa1, ka0, ka1;
    *(float4*)&xf[0] = *(const float4*)(xr + kq * 8);
    *(float4*)&xf[4] = *(const float4*)(xr + kq * 8 + 4);
    qa0 = cvt8(xf);
    *(float4*)&xf[0] = *(const float4*)(xr + 32 + kq * 8);
    *(float4*)&xf[4] = *(const float4*)(xr + 32 + kq * 8 + 4);
    qa1 = cvt8(xf);
    const float* yr = x + (size_t)(rbase + j0 + wv * 16 + m16) * 64;
    *(float4*)&xf[0] = *(const float4*)(yr + kq * 8);
    *(float4*)&xf[4] = *(const float4*)(yr + kq * 8 + 4);
    ka0 = cvt8(xf);
    *(float4*)&xf[0] = *(const float4*)(yr + 32 + kq * 8);
    *(float4*)&xf[4] = *(const float4*)(yr + 32 + kq * 8 + 4);
    ka1 = cvt8(xf);
#pragma unroll
    for (int nt = 0; nt < 4; nt++) {
      const bf16* wq = WtQ + (size_t)(nt * 16 + m16) * 64;
      f32x4 aq = (f32x4){0.f, 0.f, 0.f, 0.f};
      aq = MFMA16(qa0, *(const bf16x8*)wq, aq);
      aq = MFMA16(qa1, *(const bf16x8*)(wq + 32), aq);
      const bf16* wk = WtK + (size_t)(nt * 16 + m16) * 64;
      f32x4 ak = (f32x4){0.f, 0.f, 0.f, 0.f};
      ak = MFMA16(ka0, *(const bf16x8*)wk, ak);
      ak = MFMA16(ka1, *(const bf16x8*)(wk + 32), ak);
#pragma unroll
      for (int r = 0; r < 4; r++) {
        Qs[b][(lrow + r) * 72 + nt * 16 + m16] = __float2bfloat16(aq[r]);
        Ks[b][(lrow + r) * 72 + nt * 16 + m16] = __float2bfloat16(ak[r]);
      }
    }
  };

  proj(0, 0);
  __syncthreads();

#pragma unroll 1
  for (int rr = 0; rr < 32; rr++) {
    const int cur = rr & 1;
    if (rr < 31) proj(rr + 1, cur ^ 1);  // overlaps with dots below
#pragma unroll
    for (int ks = 0; ks < 2; ks++) {
      bf16x8 af = *(const bf16x8*)&Qs[cur][(wv * 16 + m16) * 72 + ks * 32 + kq * 8];
      bf16x8 bfr[4];
#pragma unroll
      for (int jt = 0; jt < 4; jt++)
        bfr[jt] = *(const bf16x8*)&Ks[cur][(jt * 16 + m16) * 72 + ks * 32 + kq * 8];
#pragma unroll
      for (int jt = 0; jt < 4; jt++) acc[jt] = MFMA16(af, bfr[jt], acc[jt]);
    }
    __syncthreads();  // buf^1 writes done; buf reads done -> safe to swap
  }
  const float sc = 1.f / 128.f;  // dh^-0.5 * H^-0.5
#pragma unroll
  for (int jt = 0; jt < 4; jt++)
#pragma unroll
    for (int r = 0; r < 4; r++)
      slice[(size_t)(i0 + wv * 16 + kq * 4 + r) * 256 + j0 + jt * 16 + m16] = acc[jt][r] * sc;
}

// ---------------------------------------------------------------- pair bias: LN + @W_pair -> dp slice 0
__global__ void __launch_bounds__(256) k_pb(const float* __restrict__ pb,
                                            const float* __restrict__ g,
                                            const float* __restrict__ bb,
                                            const float* __restrict__ Wp,
                                            float* __restrict__ dots) {
  __shared__ float sn[4][128];
  const int tid = threadIdx.x, lane = tid & 63, wv = tid >> 6;
  const size_t ij = (size_t)blockIdx.x * 4 + wv;
  const float2 xv = *(const float2*)(pb + ij * 128 + lane * 2);

  float s = xv.x + xv.y;
#pragma unroll
  for (int o = 1; o < 64; o <<= 1) s += __shfl_xor(s, o);
  const float mu = s * (1.f / 128.f);
  const float d0 = xv.x - mu, d1 = xv.y - mu;
  float s2 = d0 * d0 + d1 * d1;
#pragma unroll
  for (int o = 1; o < 64; o <<= 1) s2 += __shfl_xor(s2, o);
  const float inv = rsqrtf(s2 * (1.f / 128.f) + 1e-5f);

  sn[wv][lane * 2 + 0] = d0 * inv * g[lane * 2 + 0] + bb[lane * 2 + 0];
  sn[wv][lane * 2 + 1] = d1 * inv * g[lane * 2 + 1] + bb[lane * 2 + 1];

  const int h = lane & 7, gp = lane >> 3;
  float a = 0.f;
#pragma unroll
  for (int p0 = 0; p0 < 16; p0++) {
    const int p = gp * 16 + p0;
    a += sn[wv][p] * Wp[p * 8 + h];
  }
  a += __shfl_xor(a, 8);
  a += __shfl_xor(a, 16);
  a += __shfl_xor(a, 32);
  if (lane < 8) dots[(size_t)h * 65536 + ij] += a;
}

// ---------------------------------------------------------------- softmax summing 8 split-K slices -> bf16 P
__global__ void __launch_bounds__(256) k_softmax8(const float* __restrict__ dp,
                                                  bf16* __restrict__ P) {
  __shared__ float red[4];
  const int i = blockIdx.x, head = blockIdx.y, t = threadIdx.x;
  const size_t base = (size_t)head * 65536 + i * 256 + t;
  float lg = 0.f;
#pragma unroll
  for (int s = 0; s < 8; s++) lg += dp[(size_t)s * 524288 + base];
  const float e = __expf(lg);
  float s = e;
#pragma unroll
  for (int o = 1; o < 64; o <<= 1) s += __shfl_xor(s, o);
  if ((t & 63) == 0) red[t >> 6] = s;
  __syncthreads();
  const float S = red[0] + red[1] + red[2] + red[3];
  P[base] = __float2bfloat16(e / S);
}

// ---------------------------------------------------------------- FUSED height PV -> Oh (h-major)
// V projected on the fly from x; MFMA C-layout (col=d, row=j) writes the transposed
// swizzled Vt directly (free transpose).
__global__ void __launch_bounds__(256, 2)
k_h_pv_f(const bf16* __restrict__ P, const float* __restrict__ x,
         const bf16* __restrict__ Wt, bf16* __restrict__ Oh) {
  __shared__ __align__(16) bf16 Vt[64 * 256];
  const int r = blockIdx.x, head = blockIdx.y;
  const int tid = threadIdx.x, lane = tid & 63, wv = tid >> 6;
  const int m16 = lane & 15, kq = lane >> 4;

  {  // V projection: this wave computes j rows wv*64 .. +64 (x rows r*256 + j)
    const bf16* WtV = Wt + (size_t)(1024 + head * 64) * 64 + kq * 8;
#pragma unroll
    for (int mt = 0; mt < 4; mt++) {
      const int jb16 = wv * 64 + mt * 16;
      const float* xr = x + (size_t)(r * 256 + jb16 + m16) * 64;
      float xf[8];
      bf16x8 a0, a1;
      *(float4*)&xf[0] = *(const float4*)(xr + kq * 8);
      *(float4*)&xf[4] = *(const float4*)(xr + kq * 8 + 4);
      a0 = cvt8(xf);
      *(float4*)&xf[0] = *(const float4*)(xr + 32 + kq * 8);
      *(float4*)&xf[4] = *(const float4*)(xr + 32 + kq * 8 + 4);
      a1 = cvt8(xf);
#pragma unroll
      for (int nt = 0; nt < 4; nt++) {
        const int d = nt * 16 + m16;
        const bf16* wp = WtV + (size_t)(nt * 16 + m16) * 64;
        f32x4 a = (f32x4){0.f, 0.f, 0.f, 0.f};
        a = MFMA16(a0, *(const bf16x8*)wp, a);
        a = MFMA16(a1, *(const bf16x8*)(wp + 32), a);
        const int j = jb16 + kq * 4;  // 4 consecutive j (r2=0..3), same 8-granule
        bf16 tmp[4];
#pragma unroll
        for (int r2 = 0; r2 < 4; r2++) tmp[r2] = __float2bfloat16(a[r2]);
        *(uint2*)&Vt[d * 256 + (((j >> 3) ^ (d & 7)) << 3) + (j & 7)] = *(const uint2*)tmp;
      }
    }
  }

  const bf16* Pb = P + (size_t)head * 65536;
  const int i0 = wv * 64;
  auto loadP = [&](int ks, bf16x8 pf[4]) {
#pragma unroll
    for (int it = 0; it < 4; it++)
      pf[it] = *(const bf16x8*)(Pb + (size_t)(i0 + it * 16 + m16) * 256 + ks * 32 + kq * 8);
  };
  bf16x8 pcur[4];
  loadP(0, pcur);
  __syncthreads();

  f32x4 acc[4][4];
#pragma unroll
  for (int a = 0; a < 4; a++)
#pragma unroll
    for (int b = 0; b < 4; b++) acc[a][b] = (f32x4){0.f, 0.f, 0.f, 0.f};

#pragma unroll 1
  for (int ks = 0; ks < 8; ks++) {
    bf16x8 pnext[4];
    if (ks < 7) loadP(ks + 1, pnext);
    bf16x8 vf[4];
#pragma unroll
    for (int dt = 0; dt < 4; dt++)
      vf[dt] = *(const bf16x8*)&Vt[(dt * 16 + m16) * 256 + (((ks * 4 + kq) ^ (m16 & 7)) << 3)];
#pragma unroll
    for (int it = 0; it < 4; it++)
#pragma unroll
      for (int dt = 0; dt < 4; dt++) acc[it][dt] = MFMA16(pcur[it], vf[dt], acc[it][dt]);
    if (ks < 7) {
#pragma unroll
      for (int it = 0; it < 4; it++) pcur[it] = pnext[it];
    }
  }
#pragma unroll
  for (int it = 0; it < 4; it++)
#pragma unroll
    for (int dt = 0; dt < 4; dt++)
#pragma unroll
      for (int r2 = 0; r2 < 4; r2++) {
        const int i = i0 + it * 16 + kq * 4 + r2;  // w position
        Oh[((size_t)(r * 256 + i)) * 512 + head * 64 + dt * 16 + m16] =
            __float2bfloat16(acc[it][dt][r2]);
      }
}

// ---------------------------------------------------------------- final fused projection
// out[n] = 0.5*(Ow@Wout_w + Oh@Wout_h)[n] + 0.5*(bw+bh); n = h*256+w (h-major).
// Ow is w-major: its row for out-row n is ((n&255)<<8)|(n>>8).
__global__ void __launch_bounds__(256) k_outproj(const bf16* __restrict__ Ow,
                                                 const bf16* __restrict__ Oh,
                                                 const bf16* __restrict__ Wow,  // [64][512]
                                                 const bf16* __restrict__ Woh,
                                                 const float* __restrict__ bw,
                                                 const float* __restrict__ bh,
                                                 float* __restrict__ out) {
  const int tid = threadIdx.x, lane = tid & 63, wv = tid >> 6;
  const int m16 = lane & 15, kq = lane >> 4;
  const int nA = blockIdx.x * 64 + wv * 16 + m16;
  const int wA = ((nA & 255) << 8) | (nA >> 8);  // w-major remap for Ow

  const bf16* aw = Ow + (size_t)wA * 512 + kq * 8;
  const bf16* ah = Oh + (size_t)nA * 512 + kq * 8;

  f32x4 acc[4];
#pragma unroll
  for (int ct = 0; ct < 4; ct++) acc[ct] = (f32x4){0.f, 0.f, 0.f, 0.f};

#pragma unroll 1
  for (int kc = 0; kc < 16; kc++) {
    const bf16x8 afw = *(const bf16x8*)(aw + kc * 32);
    const bf16x8 afh = *(const bf16x8*)(ah + kc * 32);
#pragma unroll
    for (int ct = 0; ct < 4; ct++) {
      const bf16x8 bfw = *(const bf16x8*)(Wow + (size_t)(ct * 16 + m16) * 512 + kc * 32 + kq * 8);
      const bf16x8 bfh = *(const bf16x8*)(Woh + (size_t)(ct * 16 + m16) * 512 + kc * 32 + kq * 8);
      acc[ct] = MFMA16(afw, bfw, acc[ct]);
      acc[ct] = MFMA16(afh, bfh, acc[ct]);
    }
  }
  const int n0 = blockIdx.x * 64 + wv * 16 + kq * 4;
#pragma unroll
  for (int ct = 0; ct < 4; ct++) {
    const int c = ct * 16 + m16;
    const float bias = 0.5f * (bw[c] + bh[c]);
#pragma unroll
    for (int r = 0; r < 4; r++)
      out[(size_t)(n0 + r) * 64 + c] = 0.5f * acc[ct][r] + bias;
  }
}

// ================================================================ launch
extern "C" void kernel_launch(void* const* d_in, const int* in_sizes, int n_in,
                              void* d_out, int out_size, void* d_ws, size_t ws_size,
                              hipStream_t stream) {
  const float* x      = (const float*)d_in[0];
  const float* pair   = (const float*)d_in[1];
  const float* Wq_w   = (const float*)d_in[2];
  const float* Wkv_w  = (const float*)d_in[3];
  const float* Wout_w = (const float*)d_in[4];
  const float* bout_w = (const float*)d_in[5];
  const float* Wq_h   = (const float*)d_in[6];
  const float* Wkv_h  = (const float*)d_in[7];
  const float* Wout_h = (const float*)d_in[8];
  const float* bout_h = (const float*)d_in[9];
  const float* ln_g   = (const float*)d_in[10];
  const float* ln_b   = (const float*)d_in[11];
  const float* W_pair = (const float*)d_in[12];
  float* out = (float*)d_out;

  char* ws = (char*)d_ws;
  bf16* R0 = (bf16*)ws;                     // width Ow (w-major)
  bf16* R2 = (bf16*)(ws + 134217728);       // Oh (h-major)
  bf16* Wt = (bf16*)(ws + 201326592);       // 384K
  bf16* P  = (bf16*)(ws + 201326592 + 393216);    // 1M
  bf16* Wo_w = (bf16*)(ws + 201326592 + 1441792); // 64K
  bf16* Wo_h = Wo_w + 32768;                      // 64K
  float* dp = out;                          // d_out doubles as split-K scratch (16MB exact)

  // -------- width attention phase (fully fused QKV + attention) --------
  k_wt1<<<384, 256, 0, stream>>>(Wq_w, Wkv_w, Wt);
  k_wo<<<256, 256, 0, stream>>>(Wout_w, Wout_h, Wo_w, Wo_h);
  k_width_fused<<<dim3(WW, NHEADS), 256, 0, stream>>>(x, Wt, R0);

  // -------- height attention phase (fully fused projections) --------
  k_wt1<<<384, 256, 0, stream>>>(Wq_h, Wkv_h, Wt);
  k_dots_f<<<dim3(16, NHEADS, 8), 256, 0, stream>>>(x, Wt, dp);
  k_pb<<<65536 / 4, 256, 0, stream>>>(pair, ln_g, ln_b, W_pair, dp);  // into slice 0
  k_softmax8<<<dim3(256, NHEADS), 256, 0, stream>>>(dp, P);
  k_h_pv_f<<<dim3(HH, NHEADS), 256, 0, stream>>>(P, x, Wt, R2);       // Oh

  // -------- final fused projection (sole writer of out) --------
  k_outproj<<<1024, 256, 0, stream>>>(R0, R2, Wo_w, Wo_h, bout_w, bout_h, out);
}

// Round 10
// 524.230 us; speedup vs baseline: 1.4121x; 1.4121x over previous
//
#include <hip/hip_runtime.h>
#include <hip/hip_bf16.h>

typedef __hip_bfloat16 bf16;
typedef __attribute__((ext_vector_type(8))) short bf16x8;
typedef __attribute__((ext_vector_type(4))) float f32x4;

#define MFMA16(a, b, c) __builtin_amdgcn_mfma_f32_16x16x32_bf16(a, b, c, 0, 0, 0)

// Problem constants (B=1)
#define HH 256
#define WW 256
#define NHEADS 8
#define NROWS 65536

// ws layout:
//   R0 @ 0          (67108864): width Ow (w-major) -- written by fused width kernel
//   R1 @ 67108864   : unused
//   R2 @ 134217728  (67108864): Oh (h-major), written by k_h_pv_f
//   R3 @ 201326592  (2097152):  Wt_w (384K) @+0 | Wt_h (384K) @+393216 |
//                               P bf16 (1M) @+786432 | Wo_w/Wo_h (128K) @+1835008
//   d_out doubles as split-K dots scratch dp (8 x 2MB exact) before k_outproj overwrites it.
//
// LESSONS:
//   (R4/R5) __launch_bounds__(256, N) caps VGPRs at ~256/N on this toolchain --
//     (256,2)->128 ok; (256,3)->84 spilled acc to scratch (1.6 GB/dispatch). Never N>=3
//     for register-heavy kernels.
//   (R6) quarter K/V tiles: 2x barriers + 2x Wt re-reads, occupancy unchanged -> 126->154us.
//     R3 half-tile structure is the proven best width kernel.
//   (R2/R3/R7) the only >10% levers on this pipeline are DELETED BYTES: fusing the QKV
//     projection into its consumer (recompute from cache-resident x) beats any store/
//     load pattern tuning of the ws round trip.
//   (R7/R8) k_dots_f residency pinned ~4 blocks/CU regardless of grid; rc=16 neutral-neg.
//   (R9) source-level software pipelining (dbuf + 1 barrier/iter) REGRESSED 2.5x: proj
//     ds_writes and dots ds_reads share in-order lgkmcnt, so nothing overlapped and the
//     merged phase removed the inter-wave slack the 2-barrier form had. hipcc does not
//     preserve source pipelines -- keep the simple 2-barrier loop (139 us, proven).
//
// MFMA fragment conventions (verified m89/m91/m120):
//   A-frag: lane l holds A[m = l&15][k = (l>>4)*8 + t], t=0..7
//   B-frag: lane l holds B[n = l&15][k = (l>>4)*8 + t]
//   C/D   : lane l, reg r -> (col = l&15, row = (l>>4)*4 + r)
//   D[m][n] = sum_k A[m][k]*B[n][k]

__device__ __forceinline__ bf16x8 cvt8(const float* f) {
  bf16x8 r;
  bf16* h = (bf16*)&r;
#pragma unroll
  for (int i = 0; i < 8; i++) h[i] = __float2bfloat16(f[i]);
  return r;
}

// ---------------------------------------------------------------- Wq|Wkv transpose -> bf16 [1536][64], BOTH phases
// idx < 98304 -> width weights into Wt_w; else height weights into Wt_h.
__global__ void __launch_bounds__(256) k_wt2(const float* __restrict__ Wq_w,
                                             const float* __restrict__ Wkv_w,
                                             const float* __restrict__ Wq_h,
                                             const float* __restrict__ Wkv_h,
                                             bf16* __restrict__ Wt_w,
                                             bf16* __restrict__ Wt_h) {
  int idx = blockIdx.x * 256 + threadIdx.x;  // [0, 196608)
  const float* Wq = Wq_w;
  const float* Wkv = Wkv_w;
  bf16* Wt = Wt_w;
  if (idx >= 98304) { idx -= 98304; Wq = Wq_h; Wkv = Wkv_h; Wt = Wt_h; }
  const int k = idx / 1536, c = idx - k * 1536;
  const float val = (c < 512) ? Wq[k * 512 + c] : Wkv[k * 1024 + (c - 512)];
  Wt[(size_t)c * 64 + k] = __float2bfloat16(val);
}

// ---------------------------------------------------------------- Wout transpose -> bf16 [64][512]
__global__ void __launch_bounds__(256) k_wo(const float* __restrict__ Wout_w,
                                            const float* __restrict__ Wout_h,
                                            bf16* __restrict__ Wo_w,
                                            bf16* __restrict__ Wo_h) {
  int idx = blockIdx.x * 256 + threadIdx.x;  // [0, 65536)
  const float* W = Wout_w;
  bf16* dst = Wo_w;
  if (idx >= 32768) { idx -= 32768; W = Wout_h; dst = Wo_h; }
  const int c = idx >> 9, d = idx & 511;
  dst[idx] = __float2bfloat16(W[d * 64 + c]);  // Wo[c][d] = Wout[d][c]
}

// ---------------------------------------------------------------- FUSED width QKV + attention
// R3-proven structure (126 us): block (w, head), 4 waves, reads x directly.
// LDS 65536 (2 blocks/CU):
//   Qs [256][64] granule-XOR-swizzled @0      (32 KB) -> Ps (4x5 KB) overlays after qf load
//   Ks [128][64] granule-XOR-swizzled @32768  (16 KB) -- one 128-row HALF at a time
//   Vt [64 d][128 j] granule-XOR-swizzled @49152 (16 KB)
// Swizzle: element (row, c) at row*64 + (((c>>3) ^ (row&7))<<3) + (c&7).
__global__ void __launch_bounds__(256, 2)
k_width_fused(const float* __restrict__ x, const bf16* __restrict__ Wt,
              bf16* __restrict__ Ow) {
  __shared__ __align__(16) char smem[65536];
  bf16* Qs = (bf16*)smem;
  bf16* Ks = (bf16*)(smem + 32768);
  bf16* Vt = (bf16*)(smem + 49152);
  const int w = blockIdx.x, head = blockIdx.y;
  const int tid = threadIdx.x, lane = tid & 63, wv = tid >> 6;
  bf16* Ps = (bf16*)(smem + wv * 5120);  // overlays Qs (dead after qf load)
  const int m16 = lane & 15, kq = lane >> 4;
  const int i0 = wv * 64;

  // ---- Q phase: this wave's 64 rows (i = h), all 64 head-cols ----
  bf16x8 af[4][2];
#pragma unroll
  for (int mt = 0; mt < 4; mt++) {
    const float* xr = x + ((size_t)((i0 + mt * 16 + m16) * 256 + w)) * 64;
    float xf[8];
    *(float4*)&xf[0] = *(const float4*)(xr + kq * 8);
    *(float4*)&xf[4] = *(const float4*)(xr + kq * 8 + 4);
    af[mt][0] = cvt8(xf);
    *(float4*)&xf[0] = *(const float4*)(xr + 32 + kq * 8);
    *(float4*)&xf[4] = *(const float4*)(xr + 32 + kq * 8 + 4);
    af[mt][1] = cvt8(xf);
  }
#pragma unroll
  for (int nt = 0; nt < 4; nt++) {
    const bf16* wp = Wt + (size_t)(head * 64 + nt * 16 + m16) * 64 + kq * 8;
    const bf16x8 w0 = *(const bf16x8*)wp;
    const bf16x8 w1 = *(const bf16x8*)(wp + 32);
#pragma unroll
    for (int mt = 0; mt < 4; mt++) {
      f32x4 a = (f32x4){0.f, 0.f, 0.f, 0.f};
      a = MFMA16(af[mt][0], w0, a);
      a = MFMA16(af[mt][1], w1, a);
#pragma unroll
      for (int r = 0; r < 4; r++) {
        const int i = i0 + mt * 16 + kq * 4 + r;
        const int d = nt * 16 + m16;
        Qs[i * 64 + (((d >> 3) ^ (i & 7)) << 3) + (d & 7)] = __float2bfloat16(a[r]);
      }
    }
  }
  __syncthreads();
  // qf A-frags from own rows (swizzled read, conflict-free)
  bf16x8 qf[4][2];
#pragma unroll
  for (int it = 0; it < 4; it++)
#pragma unroll
    for (int ks = 0; ks < 2; ks++)
      qf[it][ks] = *(const bf16x8*)&Qs[(i0 + it * 16 + m16) * 64 +
                                       (((ks * 4 + kq) ^ (m16 & 7)) << 3)];

  f32x4 acc[4][4];
#pragma unroll
  for (int a = 0; a < 4; a++)
#pragma unroll
    for (int b = 0; b < 4; b++) acc[a][b] = (f32x4){0.f, 0.f, 0.f, 0.f};
  float rsum[4][4];
#pragma unroll
  for (int a = 0; a < 4; a++)
#pragma unroll
    for (int r = 0; r < 4; r++) rsum[a][r] = 0.f;

#pragma unroll 1
  for (int half = 0; half < 2; half++) {
    if (half) __syncthreads();  // all reads of prior half's Ks/Vt done
    // ---- K/V phase: this wave computes 32 rows (local j = wv*32..+32) of this half ----
    bf16x8 afk[2][2];
#pragma unroll
    for (int mt = 0; mt < 2; mt++) {
      const int jrow = half * 128 + wv * 32 + mt * 16 + m16;  // global j (= h)
      const float* xr = x + ((size_t)(jrow * 256 + w)) * 64;
      float xf[8];
      *(float4*)&xf[0] = *(const float4*)(xr + kq * 8);
      *(float4*)&xf[4] = *(const float4*)(xr + kq * 8 + 4);
      afk[mt][0] = cvt8(xf);
      *(float4*)&xf[0] = *(const float4*)(xr + 32 + kq * 8);
      *(float4*)&xf[4] = *(const float4*)(xr + 32 + kq * 8 + 4);
      afk[mt][1] = cvt8(xf);
    }
#pragma unroll
    for (int nt = 0; nt < 4; nt++) {
      const int d = nt * 16 + m16;
      {  // K -> Ks
        const bf16* wp = Wt + (size_t)(512 + head * 64 + d) * 64 + kq * 8;
        const bf16x8 w0 = *(const bf16x8*)wp;
        const bf16x8 w1 = *(const bf16x8*)(wp + 32);
#pragma unroll
        for (int mt = 0; mt < 2; mt++) {
          f32x4 a = (f32x4){0.f, 0.f, 0.f, 0.f};
          a = MFMA16(afk[mt][0], w0, a);
          a = MFMA16(afk[mt][1], w1, a);
#pragma unroll
          for (int r = 0; r < 4; r++) {
            const int jl = wv * 32 + mt * 16 + kq * 4 + r;  // local row in half
            Ks[jl * 64 + (((d >> 3) ^ (jl & 7)) << 3) + (d & 7)] = __float2bfloat16(a[r]);
          }
        }
      }
      {  // V -> Vt (transposed), 4 consecutive j packed as 8 B
        const bf16* wp = Wt + (size_t)(1024 + head * 64 + d) * 64 + kq * 8;
        const bf16x8 w0 = *(const bf16x8*)wp;
        const bf16x8 w1 = *(const bf16x8*)(wp + 32);
#pragma unroll
        for (int mt = 0; mt < 2; mt++) {
          f32x4 a = (f32x4){0.f, 0.f, 0.f, 0.f};
          a = MFMA16(afk[mt][0], w0, a);
          a = MFMA16(afk[mt][1], w1, a);
          const int jb = wv * 32 + mt * 16 + kq * 4;  // local j base (r=0..3)
          bf16 tmp[4];
#pragma unroll
          for (int r = 0; r < 4; r++) tmp[r] = __float2bfloat16(a[r]);
          *(uint2*)&Vt[d * 128 + (((jb >> 3) ^ (d & 7)) << 3) + (jb & 7)] =
              *(const uint2*)tmp;
        }
      }
    }
    __syncthreads();
    // ---- attention over this half's 128 j ----
#pragma unroll 1
    for (int jcl = 0; jcl < 4; jcl++) {
      bf16x8 kf[2][2];
#pragma unroll
      for (int jt = 0; jt < 2; jt++) {
        const int j = jcl * 32 + jt * 16 + m16;  // local row in half
#pragma unroll
        for (int ks = 0; ks < 2; ks++)
          kf[jt][ks] = *(const bf16x8*)&Ks[j * 64 + (((ks * 4 + kq) ^ (j & 7)) << 3)];
      }
#pragma unroll
      for (int it = 0; it < 4; it++)
#pragma unroll
        for (int jt = 0; jt < 2; jt++) {
          f32x4 s = (f32x4){0.f, 0.f, 0.f, 0.f};
          s = MFMA16(qf[it][0], kf[jt][0], s);
          s = MFMA16(qf[it][1], kf[jt][1], s);
#pragma unroll
          for (int r = 0; r < 4; r++) {
            float p = __expf(s[r] * 0.125f);
            rsum[it][r] += p;
            Ps[(it * 16 + kq * 4 + r) * 40 + jt * 16 + m16] = __float2bfloat16(p);
          }
        }
      bf16x8 pf[4], vf[4];
#pragma unroll
      for (int it = 0; it < 4; it++)
        pf[it] = *(const bf16x8*)&Ps[(it * 16 + m16) * 40 + kq * 8];
#pragma unroll
      for (int dt = 0; dt < 4; dt++)
        vf[dt] = *(const bf16x8*)&Vt[(dt * 16 + m16) * 128 +
                                     (((jcl * 4 + kq) ^ (m16 & 7)) << 3)];
#pragma unroll
      for (int it = 0; it < 4; it++)
#pragma unroll
        for (int dt = 0; dt < 4; dt++) acc[it][dt] = MFMA16(pf[it], vf[dt], acc[it][dt]);
    }
  }

#pragma unroll
  for (int it = 0; it < 4; it++)
#pragma unroll
    for (int r = 0; r < 4; r++) {
      float s = rsum[it][r];
      s += __shfl_xor(s, 1); s += __shfl_xor(s, 2);
      s += __shfl_xor(s, 4); s += __shfl_xor(s, 8);
      rsum[it][r] = 1.f / s;
    }
#pragma unroll
  for (int it = 0; it < 4; it++)
#pragma unroll
    for (int dt = 0; dt < 4; dt++)
#pragma unroll
      for (int r = 0; r < 4; r++) {
        const int i = i0 + it * 16 + kq * 4 + r;  // = h
        Ow[((size_t)(w * 256 + i)) * 512 + head * 64 + dt * 16 + m16] =
            __float2bfloat16(acc[it][dt][r] * rsum[it][r]);
      }
}

// ---------------------------------------------------------------- FUSED height tied dots (split-K)
// R7-proven form (139 us): on-the-fly Q/K projection from x, simple 2-barrier loop.
// grid (16 tiles 64x64, 8 heads, 8 rc), block 256 = 4 waves.
__global__ void __launch_bounds__(256, 2)
k_dots_f(const float* __restrict__ x, const bf16* __restrict__ Wt, float* __restrict__ dp) {
  __shared__ __align__(16) bf16 Qs[64 * 72];
  __shared__ __align__(16) bf16 Ks[64 * 72];
  const int tile = blockIdx.x, head = blockIdx.y, rc = blockIdx.z;
  const int i0 = (tile >> 2) * 64, j0 = (tile & 3) * 64;
  const int tid = threadIdx.x, lane = tid & 63, wv = tid >> 6;
  const int m16 = lane & 15, kq = lane >> 4;
  float* slice = dp + (size_t)rc * 524288 + (size_t)head * 65536;

  const bf16* WtQ = Wt + (size_t)(head * 64) * 64 + kq * 8;
  const bf16* WtK = Wt + (size_t)(512 + head * 64) * 64 + kq * 8;

  f32x4 acc[4];
#pragma unroll
  for (int b = 0; b < 4; b++) acc[b] = (f32x4){0.f, 0.f, 0.f, 0.f};

  const int lrow = wv * 16 + kq * 4;

#pragma unroll 1
  for (int rr = 0; rr < 32; rr++) {
    const int rbase = (rc * 32 + rr) * 256;
    __syncthreads();  // prior iteration's dots reads done
    {
      // q-rows: x rows rbase + i0 + wv*16 + m16 (contiguous per wave)
      const float* xr = x + (size_t)(rbase + i0 + wv * 16 + m16) * 64;
      float xf[8];
      bf16x8 qa0, qa1, ka0, ka1;
      *(float4*)&xf[0] = *(const float4*)(xr + kq * 8);
      *(float4*)&xf[4] = *(const float4*)(xr + kq * 8 + 4);
      qa0 = cvt8(xf);
      *(float4*)&xf[0] = *(const float4*)(xr + 32 + kq * 8);
      *(float4*)&xf[4] = *(const float4*)(xr + 32 + kq * 8 + 4);
      qa1 = cvt8(xf);
      const float* yr = x + (size_t)(rbase + j0 + wv * 16 + m16) * 64;
      *(float4*)&xf[0] = *(const float4*)(yr + kq * 8);
      *(float4*)&xf[4] = *(const float4*)(yr + kq * 8 + 4);
      ka0 = cvt8(xf);
      *(float4*)&xf[0] = *(const float4*)(yr + 32 + kq * 8);
      *(float4*)&xf[4] = *(const float4*)(yr + 32 + kq * 8 + 4);
      ka1 = cvt8(xf);
#pragma unroll
      for (int nt = 0; nt < 4; nt++) {
        const bf16* wq = WtQ + (size_t)(nt * 16 + m16) * 64;
        f32x4 aq = (f32x4){0.f, 0.f, 0.f, 0.f};
        aq = MFMA16(qa0, *(const bf16x8*)wq, aq);
        aq = MFMA16(qa1, *(const bf16x8*)(wq + 32), aq);
        const bf16* wk = WtK + (size_t)(nt * 16 + m16) * 64;
        f32x4 ak = (f32x4){0.f, 0.f, 0.f, 0.f};
        ak = MFMA16(ka0, *(const bf16x8*)wk, ak);
        ak = MFMA16(ka1, *(const bf16x8*)(wk + 32), ak);
#pragma unroll
        for (int r = 0; r < 4; r++) {
          Qs[(lrow + r) * 72 + nt * 16 + m16] = __float2bfloat16(aq[r]);
          Ks[(lrow + r) * 72 + nt * 16 + m16] = __float2bfloat16(ak[r]);
        }
      }
    }
    __syncthreads();
#pragma unroll
    for (int ks = 0; ks < 2; ks++) {
      bf16x8 af = *(const bf16x8*)&Qs[(wv * 16 + m16) * 72 + ks * 32 + kq * 8];
      bf16x8 bfr[4];
#pragma unroll
      for (int jt = 0; jt < 4; jt++)
        bfr[jt] = *(const bf16x8*)&Ks[(jt * 16 + m16) * 72 + ks * 32 + kq * 8];
#pragma unroll
      for (int jt = 0; jt < 4; jt++) acc[jt] = MFMA16(af, bfr[jt], acc[jt]);
    }
  }
  const float sc = 1.f / 128.f;  // dh^-0.5 * H^-0.5
#pragma unroll
  for (int jt = 0; jt < 4; jt++)
#pragma unroll
    for (int r = 0; r < 4; r++)
      slice[(size_t)(i0 + wv * 16 + kq * 4 + r) * 256 + j0 + jt * 16 + m16] = acc[jt][r] * sc;
}

// ---------------------------------------------------------------- pair bias: LN + @W_pair -> dp slice 0
__global__ void __launch_bounds__(256) k_pb(const float* __restrict__ pb,
                                            const float* __restrict__ g,
                                            const float* __restrict__ bb,
                                            const float* __restrict__ Wp,
                                            float* __restrict__ dots) {
  __shared__ float sn[4][128];
  const int tid = threadIdx.x, lane = tid & 63, wv = tid >> 6;
  const size_t ij = (size_t)blockIdx.x * 4 + wv;
  const float2 xv = *(const float2*)(pb + ij * 128 + lane * 2);

  float s = xv.x + xv.y;
#pragma unroll
  for (int o = 1; o < 64; o <<= 1) s += __shfl_xor(s, o);
  const float mu = s * (1.f / 128.f);
  const float d0 = xv.x - mu, d1 = xv.y - mu;
  float s2 = d0 * d0 + d1 * d1;
#pragma unroll
  for (int o = 1; o < 64; o <<= 1) s2 += __shfl_xor(s2, o);
  const float inv = rsqrtf(s2 * (1.f / 128.f) + 1e-5f);

  sn[wv][lane * 2 + 0] = d0 * inv * g[lane * 2 + 0] + bb[lane * 2 + 0];
  sn[wv][lane * 2 + 1] = d1 * inv * g[lane * 2 + 1] + bb[lane * 2 + 1];

  const int h = lane & 7, gp = lane >> 3;
  float a = 0.f;
#pragma unroll
  for (int p0 = 0; p0 < 16; p0++) {
    const int p = gp * 16 + p0;
    a += sn[wv][p] * Wp[p * 8 + h];
  }
  a += __shfl_xor(a, 8);
  a += __shfl_xor(a, 16);
  a += __shfl_xor(a, 32);
  if (lane < 8) dots[(size_t)h * 65536 + ij] += a;
}

// ---------------------------------------------------------------- softmax summing 8 split-K slices -> bf16 P
__global__ void __launch_bounds__(256) k_softmax8(const float* __restrict__ dp,
                                                  bf16* __restrict__ P) {
  __shared__ float red[4];
  const int i = blockIdx.x, head = blockIdx.y, t = threadIdx.x;
  const size_t base = (size_t)head * 65536 + i * 256 + t;
  float lg = 0.f;
#pragma unroll
  for (int s = 0; s < 8; s++) lg += dp[(size_t)s * 524288 + base];
  const float e = __expf(lg);
  float s = e;
#pragma unroll
  for (int o = 1; o < 64; o <<= 1) s += __shfl_xor(s, o);
  if ((t & 63) == 0) red[t >> 6] = s;
  __syncthreads();
  const float S = red[0] + red[1] + red[2] + red[3];
  P[base] = __float2bfloat16(e / S);
}

// ---------------------------------------------------------------- FUSED height PV -> Oh (h-major)
// V projected on the fly from x; MFMA C-layout (col=d, row=j) writes the transposed
// swizzled Vt directly (free transpose).
__global__ void __launch_bounds__(256, 2)
k_h_pv_f(const bf16* __restrict__ P, const float* __restrict__ x,
         const bf16* __restrict__ Wt, bf16* __restrict__ Oh) {
  __shared__ __align__(16) bf16 Vt[64 * 256];
  const int r = blockIdx.x, head = blockIdx.y;
  const int tid = threadIdx.x, lane = tid & 63, wv = tid >> 6;
  const int m16 = lane & 15, kq = lane >> 4;

  {  // V projection: this wave computes j rows wv*64 .. +64 (x rows r*256 + j)
    const bf16* WtV = Wt + (size_t)(1024 + head * 64) * 64 + kq * 8;
#pragma unroll
    for (int mt = 0; mt < 4; mt++) {
      const int jb16 = wv * 64 + mt * 16;
      const float* xr = x + (size_t)(r * 256 + jb16 + m16) * 64;
      float xf[8];
      bf16x8 a0, a1;
      *(float4*)&xf[0] = *(const float4*)(xr + kq * 8);
      *(float4*)&xf[4] = *(const float4*)(xr + kq * 8 + 4);
      a0 = cvt8(xf);
      *(float4*)&xf[0] = *(const float4*)(xr + 32 + kq * 8);
      *(float4*)&xf[4] = *(const float4*)(xr + 32 + kq * 8 + 4);
      a1 = cvt8(xf);
#pragma unroll
      for (int nt = 0; nt < 4; nt++) {
        const int d = nt * 16 + m16;
        const bf16* wp = WtV + (size_t)(nt * 16 + m16) * 64;
        f32x4 a = (f32x4){0.f, 0.f, 0.f, 0.f};
        a = MFMA16(a0, *(const bf16x8*)wp, a);
        a = MFMA16(a1, *(const bf16x8*)(wp + 32), a);
        const int j = jb16 + kq * 4;  // 4 consecutive j (r2=0..3), same 8-granule
        bf16 tmp[4];
#pragma unroll
        for (int r2 = 0; r2 < 4; r2++) tmp[r2] = __float2bfloat16(a[r2]);
        *(uint2*)&Vt[d * 256 + (((j >> 3) ^ (d & 7)) << 3) + (j & 7)] = *(const uint2*)tmp;
      }
    }
  }

  const bf16* Pb = P + (size_t)head * 65536;
  const int i0 = wv * 64;
  auto loadP = [&](int ks, bf16x8 pf[4]) {
#pragma unroll
    for (int it = 0; it < 4; it++)
      pf[it] = *(const bf16x8*)(Pb + (size_t)(i0 + it * 16 + m16) * 256 + ks * 32 + kq * 8);
  };
  bf16x8 pcur[4];
  loadP(0, pcur);
  __syncthreads();

  f32x4 acc[4][4];
#pragma unroll
  for (int a = 0; a < 4; a++)
#pragma unroll
    for (int b = 0; b < 4; b++) acc[a][b] = (f32x4){0.f, 0.f, 0.f, 0.f};

#pragma unroll 1
  for (int ks = 0; ks < 8; ks++) {
    bf16x8 pnext[4];
    if (ks < 7) loadP(ks + 1, pnext);
    bf16x8 vf[4];
#pragma unroll
    for (int dt = 0; dt < 4; dt++)
      vf[dt] = *(const bf16x8*)&Vt[(dt * 16 + m16) * 256 + (((ks * 4 + kq) ^ (m16 & 7)) << 3)];
#pragma unroll
    for (int it = 0; it < 4; it++)
#pragma unroll
      for (int dt = 0; dt < 4; dt++) acc[it][dt] = MFMA16(pcur[it], vf[dt], acc[it][dt]);
    if (ks < 7) {
#pragma unroll
      for (int it = 0; it < 4; it++) pcur[it] = pnext[it];
    }
  }
#pragma unroll
  for (int it = 0; it < 4; it++)
#pragma unroll
    for (int dt = 0; dt < 4; dt++)
#pragma unroll
      for (int r2 = 0; r2 < 4; r2++) {
        const int i = i0 + it * 16 + kq * 4 + r2;  // w position
        Oh[((size_t)(r * 256 + i)) * 512 + head * 64 + dt * 16 + m16] =
            __float2bfloat16(acc[it][dt][r2]);
      }
}

// ---------------------------------------------------------------- final fused projection
// out[n] = 0.5*(Ow@Wout_w + Oh@Wout_h)[n] + 0.5*(bw+bh); n = h*256+w (h-major).
// Ow is w-major: its row for out-row n is ((n&255)<<8)|(n>>8).
__global__ void __launch_bounds__(256) k_outproj(const bf16* __restrict__ Ow,
                                                 const bf16* __restrict__ Oh,
                                                 const bf16* __restrict__ Wow,  // [64][512]
                                                 const bf16* __restrict__ Woh,
                                                 const float* __restrict__ bw,
                                                 const float* __restrict__ bh,
                                                 float* __restrict__ out) {
  const int tid = threadIdx.x, lane = tid & 63, wv = tid >> 6;
  const int m16 = lane & 15, kq = lane >> 4;
  const int nA = blockIdx.x * 64 + wv * 16 + m16;
  const int wA = ((nA & 255) << 8) | (nA >> 8);  // w-major remap for Ow

  const bf16* aw = Ow + (size_t)wA * 512 + kq * 8;
  const bf16* ah = Oh + (size_t)nA * 512 + kq * 8;

  f32x4 acc[4];
#pragma unroll
  for (int ct = 0; ct < 4; ct++) acc[ct] = (f32x4){0.f, 0.f, 0.f, 0.f};

#pragma unroll 1
  for (int kc = 0; kc < 16; kc++) {
    const bf16x8 afw = *(const bf16x8*)(aw + kc * 32);
    const bf16x8 afh = *(const bf16x8*)(ah + kc * 32);
#pragma unroll
    for (int ct = 0; ct < 4; ct++) {
      const bf16x8 bfw = *(const bf16x8*)(Wow + (size_t)(ct * 16 + m16) * 512 + kc * 32 + kq * 8);
      const bf16x8 bfh = *(const bf16x8*)(Woh + (size_t)(ct * 16 + m16) * 512 + kc * 32 + kq * 8);
      acc[ct] = MFMA16(afw, bfw, acc[ct]);
      acc[ct] = MFMA16(afh, bfh, acc[ct]);
    }
  }
  const int n0 = blockIdx.x * 64 + wv * 16 + kq * 4;
#pragma unroll
  for (int ct = 0; ct < 4; ct++) {
    const int c = ct * 16 + m16;
    const float bias = 0.5f * (bw[c] + bh[c]);
#pragma unroll
    for (int r = 0; r < 4; r++)
      out[(size_t)(n0 + r) * 64 + c] = 0.5f * acc[ct][r] + bias;
  }
}

// ================================================================ launch
extern "C" void kernel_launch(void* const* d_in, const int* in_sizes, int n_in,
                              void* d_out, int out_size, void* d_ws, size_t ws_size,
                              hipStream_t stream) {
  const float* x      = (const float*)d_in[0];
  const float* pair   = (const float*)d_in[1];
  const float* Wq_w   = (const float*)d_in[2];
  const float* Wkv_w  = (const float*)d_in[3];
  const float* Wout_w = (const float*)d_in[4];
  const float* bout_w = (const float*)d_in[5];
  const float* Wq_h   = (const float*)d_in[6];
  const float* Wkv_h  = (const float*)d_in[7];
  const float* Wout_h = (const float*)d_in[8];
  const float* bout_h = (const float*)d_in[9];
  const float* ln_g   = (const float*)d_in[10];
  const float* ln_b   = (const float*)d_in[11];
  const float* W_pair = (const float*)d_in[12];
  float* out = (float*)d_out;

  char* ws = (char*)d_ws;
  bf16* R0 = (bf16*)ws;                     // width Ow (w-major)
  bf16* R2 = (bf16*)(ws + 134217728);       // Oh (h-major)
  bf16* Wt_w = (bf16*)(ws + 201326592);           // 384K
  bf16* Wt_h = (bf16*)(ws + 201326592 + 393216);  // 384K
  bf16* P  = (bf16*)(ws + 201326592 + 786432);    // 1M
  bf16* Wo_w = (bf16*)(ws + 201326592 + 1835008); // 64K
  bf16* Wo_h = Wo_w + 32768;                      // 64K
  float* dp = out;                          // d_out doubles as split-K scratch (16MB exact)

  // -------- weight prep (both phases, up front) --------
  k_wt2<<<768, 256, 0, stream>>>(Wq_w, Wkv_w, Wq_h, Wkv_h, Wt_w, Wt_h);
  k_wo<<<256, 256, 0, stream>>>(Wout_w, Wout_h, Wo_w, Wo_h);

  // -------- width attention phase (fully fused QKV + attention) --------
  k_width_fused<<<dim3(WW, NHEADS), 256, 0, stream>>>(x, Wt_w, R0);

  // -------- height attention phase (fully fused projections) --------
  k_dots_f<<<dim3(16, NHEADS, 8), 256, 0, stream>>>(x, Wt_h, dp);
  k_pb<<<65536 / 4, 256, 0, stream>>>(pair, ln_g, ln_b, W_pair, dp);  // into slice 0
  k_softmax8<<<dim3(256, NHEADS), 256, 0, stream>>>(dp, P);
  k_h_pv_f<<<dim3(HH, NHEADS), 256, 0, stream>>>(P, x, Wt_h, R2);     // Oh

  // -------- final fused projection (sole writer of out) --------
  k_outproj<<<1024, 256, 0, stream>>>(R0, R2, Wo_w, Wo_h, bout_w, bout_h, out);
}

// Round 12
// 445.691 us; speedup vs baseline: 1.6609x; 1.1762x over previous
//
#include <hip/hip_runtime.h>
#include <hip/hip_bf16.h>

typedef __hip_bfloat16 bf16;
typedef __attribute__((ext_vector_type(8))) short bf16x8;
typedef __attribute__((ext_vector_type(4))) float f32x4;

#define MFMA16(a, b, c) __builtin_amdgcn_mfma_f32_16x16x32_bf16(a, b, c, 0, 0, 0)

// Problem constants (B=1)
#define HH 256
#define WW 256
#define NHEADS 8
#define NROWS 65536

// ws layout:
//   R0 @ 0          (67108864): width Ow (w-major) -- written by fused width kernel
//   R1 @ 67108864   (67108864): xh bf16 (8MB) @+0 | xw bf16 (8MB) @+8388608
//   R2 @ 134217728  (67108864): Oh (h-major), written by k_h_pv_f
//   R3 @ 201326592  (2097152):  Wt_w (384K) @+0 | Wt_h (384K) @+393216 |
//                               P bf16 (1M) @+786432 | Wo_w/Wo_h (128K) @+1835008
//   d_out doubles as split-K dots scratch dp (8 x 2MB exact) before k_outproj overwrites it.
//
// LESSONS:
//   (R4/R5) __launch_bounds__(256, N) caps VGPRs at ~256/N on this toolchain --
//     (256,2)->128 ok; (256,3)->84 spilled acc to scratch (1.6 GB/dispatch). Never N>=3
//     for register-heavy kernels. NOTE: R4's "workspace staging costs 1GB" lesson was
//     a MISDIAGNOSIS -- the traffic was spill (R4 also used (256,3)); R12 retests
//     bf16 x-staging spill-free.
//   (R6) quarter K/V tiles: 2x barriers + 2x Wt re-reads, occupancy unchanged -> 126->154us.
//     R3 half-tile structure is the proven best width kernel.
//   (R2/R3/R7) the only >10% levers on this pipeline are DELETED BYTES: fusing the QKV
//     projection into its consumer (recompute from cache-resident x) beats any store/
//     load pattern tuning of the ws round trip.
//   (R7/R8) k_dots_f residency pinned ~4 blocks/CU regardless of grid; rc=16 neutral-neg.
//   (R9) source-level software pipelining (dbuf + 1 barrier/iter) REGRESSED 2.5x: proj
//     ds_writes and dots ds_reads share in-order lgkmcnt, so nothing overlapped and the
//     merged phase removed the inter-wave slack the 2-barrier form had. hipcc does not
//     preserve source pipelines -- keep the simple 2-barrier loop (139 us, proven).
//   (R11) k_xT2 grid was 4x oversized (16384 vs 4096) -> OOB read of x -> abort.
//     ALWAYS: grid*block*elems_per_thread == buffer element count, check on every new kernel.
//
// MFMA fragment conventions (verified m89/m91/m120):
//   A-frag: lane l holds A[m = l&15][k = (l>>4)*8 + t], t=0..7
//   B-frag: lane l holds B[n = l&15][k = (l>>4)*8 + t]
//   C/D   : lane l, reg r -> (col = l&15, row = (l>>4)*4 + r)
//   D[m][n] = sum_k A[m][k]*B[n][k]

__device__ __forceinline__ bf16x8 cvt8(const float* f) {
  bf16x8 r;
  bf16* h = (bf16*)&r;
#pragma unroll
  for (int i = 0; i < 8; i++) h[i] = __float2bfloat16(f[i]);
  return r;
}

// ---------------------------------------------------------------- x -> bf16, both layouts
// x has 4,194,304 floats; 4/thread -> grid 4096 x 256.
// xh[n][d] = bf16(x[n][d]) (h-major, coalesced); xw[(w<<8|h)][d] = same values, w-major.
// Rounding identical to the old in-register cvt8 path -> bitwise-same results downstream.
__global__ void __launch_bounds__(256) k_xT2(const float* __restrict__ x,
                                             bf16* __restrict__ xh,
                                             bf16* __restrict__ xw) {
  const size_t idx = ((size_t)blockIdx.x * 256 + threadIdx.x) * 4;
  const float4 v = *(const float4*)(x + idx);
  bf16 tmp[4];
  tmp[0] = __float2bfloat16(v.x);
  tmp[1] = __float2bfloat16(v.y);
  tmp[2] = __float2bfloat16(v.z);
  tmp[3] = __float2bfloat16(v.w);
  *(uint2*)(xh + idx) = *(const uint2*)tmp;
  const int n = (int)(idx >> 6), d = (int)(idx & 63);
  const int h = n >> 8, w = n & 255;
  *(uint2*)(xw + (((size_t)((w << 8) | h)) << 6) + d) = *(const uint2*)tmp;
}

// ---------------------------------------------------------------- Wq|Wkv transpose -> bf16 [1536][64], BOTH phases
__global__ void __launch_bounds__(256) k_wt2(const float* __restrict__ Wq_w,
                                             const float* __restrict__ Wkv_w,
                                             const float* __restrict__ Wq_h,
                                             const float* __restrict__ Wkv_h,
                                             bf16* __restrict__ Wt_w,
                                             bf16* __restrict__ Wt_h) {
  int idx = blockIdx.x * 256 + threadIdx.x;  // [0, 196608)
  const float* Wq = Wq_w;
  const float* Wkv = Wkv_w;
  bf16* Wt = Wt_w;
  if (idx >= 98304) { idx -= 98304; Wq = Wq_h; Wkv = Wkv_h; Wt = Wt_h; }
  const int k = idx / 1536, c = idx - k * 1536;
  const float val = (c < 512) ? Wq[k * 512 + c] : Wkv[k * 1024 + (c - 512)];
  Wt[(size_t)c * 64 + k] = __float2bfloat16(val);
}

// ---------------------------------------------------------------- Wout transpose -> bf16 [64][512]
__global__ void __launch_bounds__(256) k_wo(const float* __restrict__ Wout_w,
                                            const float* __restrict__ Wout_h,
                                            bf16* __restrict__ Wo_w,
                                            bf16* __restrict__ Wo_h) {
  int idx = blockIdx.x * 256 + threadIdx.x;  // [0, 65536)
  const float* W = Wout_w;
  bf16* dst = Wo_w;
  if (idx >= 32768) { idx -= 32768; W = Wout_h; dst = Wo_h; }
  const int c = idx >> 9, d = idx & 511;
  dst[idx] = __float2bfloat16(W[d * 64 + c]);  // Wo[c][d] = Wout[d][c]
}

// ---------------------------------------------------------------- FUSED width QKV + attention
// R3-proven structure, now reading pre-cast w-major bf16 xw (contiguous rows: one
// bf16x8 per fragment instead of two float4 + cvt8 from 64KB-strided fp32 gathers).
// LDS 65536 (2 blocks/CU):
//   Qs [256][64] granule-XOR-swizzled @0      (32 KB) -> Ps (4x5 KB) overlays after qf load
//   Ks [128][64] granule-XOR-swizzled @32768  (16 KB) -- one 128-row HALF at a time
//   Vt [64 d][128 j] granule-XOR-swizzled @49152 (16 KB)
// Swizzle: element (row, c) at row*64 + (((c>>3) ^ (row&7))<<3) + (c&7).
__global__ void __launch_bounds__(256, 2)
k_width_fused(const bf16* __restrict__ xw, const bf16* __restrict__ Wt,
              bf16* __restrict__ Ow) {
  __shared__ __align__(16) char smem[65536];
  bf16* Qs = (bf16*)smem;
  bf16* Ks = (bf16*)(smem + 32768);
  bf16* Vt = (bf16*)(smem + 49152);
  const int w = blockIdx.x, head = blockIdx.y;
  const int tid = threadIdx.x, lane = tid & 63, wv = tid >> 6;
  bf16* Ps = (bf16*)(smem + wv * 5120);  // overlays Qs (dead after qf load)
  const int m16 = lane & 15, kq = lane >> 4;
  const int i0 = wv * 64;
  const bf16* xcol = xw + (size_t)w * 256 * 64;  // [h][64] contiguous

  // ---- Q phase: this wave's 64 rows (i = h), all 64 head-cols ----
  bf16x8 af[4][2];
#pragma unroll
  for (int mt = 0; mt < 4; mt++) {
    const bf16* xr = xcol + (size_t)(i0 + mt * 16 + m16) * 64 + kq * 8;
    af[mt][0] = *(const bf16x8*)xr;
    af[mt][1] = *(const bf16x8*)(xr + 32);
  }
#pragma unroll
  for (int nt = 0; nt < 4; nt++) {
    const bf16* wp = Wt + (size_t)(head * 64 + nt * 16 + m16) * 64 + kq * 8;
    const bf16x8 w0 = *(const bf16x8*)wp;
    const bf16x8 w1 = *(const bf16x8*)(wp + 32);
#pragma unroll
    for (int mt = 0; mt < 4; mt++) {
      f32x4 a = (f32x4){0.f, 0.f, 0.f, 0.f};
      a = MFMA16(af[mt][0], w0, a);
      a = MFMA16(af[mt][1], w1, a);
#pragma unroll
      for (int r = 0; r < 4; r++) {
        const int i = i0 + mt * 16 + kq * 4 + r;
        const int d = nt * 16 + m16;
        Qs[i * 64 + (((d >> 3) ^ (i & 7)) << 3) + (d & 7)] = __float2bfloat16(a[r]);
      }
    }
  }
  __syncthreads();
  // qf A-frags from own rows (swizzled read, conflict-free)
  bf16x8 qf[4][2];
#pragma unroll
  for (int it = 0; it < 4; it++)
#pragma unroll
    for (int ks = 0; ks < 2; ks++)
      qf[it][ks] = *(const bf16x8*)&Qs[(i0 + it * 16 + m16) * 64 +
                                       (((ks * 4 + kq) ^ (m16 & 7)) << 3)];

  f32x4 acc[4][4];
#pragma unroll
  for (int a = 0; a < 4; a++)
#pragma unroll
    for (int b = 0; b < 4; b++) acc[a][b] = (f32x4){0.f, 0.f, 0.f, 0.f};
  float rsum[4][4];
#pragma unroll
  for (int a = 0; a < 4; a++)
#pragma unroll
    for (int r = 0; r < 4; r++) rsum[a][r] = 0.f;

#pragma unroll 1
  for (int half = 0; half < 2; half++) {
    if (half) __syncthreads();  // all reads of prior half's Ks/Vt done
    // ---- K/V phase: this wave computes 32 rows (local j = wv*32..+32) of this half ----
    bf16x8 afk[2][2];
#pragma unroll
    for (int mt = 0; mt < 2; mt++) {
      const int jrow = half * 128 + wv * 32 + mt * 16 + m16;  // global j (= h)
      const bf16* xr = xcol + (size_t)jrow * 64 + kq * 8;
      afk[mt][0] = *(const bf16x8*)xr;
      afk[mt][1] = *(const bf16x8*)(xr + 32);
    }
#pragma unroll
    for (int nt = 0; nt < 4; nt++) {
      const int d = nt * 16 + m16;
      {  // K -> Ks
        const bf16* wp = Wt + (size_t)(512 + head * 64 + d) * 64 + kq * 8;
        const bf16x8 w0 = *(const bf16x8*)wp;
        const bf16x8 w1 = *(const bf16x8*)(wp + 32);
#pragma unroll
        for (int mt = 0; mt < 2; mt++) {
          f32x4 a = (f32x4){0.f, 0.f, 0.f, 0.f};
          a = MFMA16(afk[mt][0], w0, a);
          a = MFMA16(afk[mt][1], w1, a);
#pragma unroll
          for (int r = 0; r < 4; r++) {
            const int jl = wv * 32 + mt * 16 + kq * 4 + r;  // local row in half
            Ks[jl * 64 + (((d >> 3) ^ (jl & 7)) << 3) + (d & 7)] = __float2bfloat16(a[r]);
          }
        }
      }
      {  // V -> Vt (transposed), 4 consecutive j packed as 8 B
        const bf16* wp = Wt + (size_t)(1024 + head * 64 + d) * 64 + kq * 8;
        const bf16x8 w0 = *(const bf16x8*)wp;
        const bf16x8 w1 = *(const bf16x8*)(wp + 32);
#pragma unroll
        for (int mt = 0; mt < 2; mt++) {
          f32x4 a = (f32x4){0.f, 0.f, 0.f, 0.f};
          a = MFMA16(afk[mt][0], w0, a);
          a = MFMA16(afk[mt][1], w1, a);
          const int jb = wv * 32 + mt * 16 + kq * 4;  // local j base (r=0..3)
          bf16 tmp[4];
#pragma unroll
          for (int r = 0; r < 4; r++) tmp[r] = __float2bfloat16(a[r]);
          *(uint2*)&Vt[d * 128 + (((jb >> 3) ^ (d & 7)) << 3) + (jb & 7)] =
              *(const uint2*)tmp;
        }
      }
    }
    __syncthreads();
    // ---- attention over this half's 128 j ----
#pragma unroll 1
    for (int jcl = 0; jcl < 4; jcl++) {
      bf16x8 kf[2][2];
#pragma unroll
      for (int jt = 0; jt < 2; jt++) {
        const int j = jcl * 32 + jt * 16 + m16;  // local row in half
#pragma unroll
        for (int ks = 0; ks < 2; ks++)
          kf[jt][ks] = *(const bf16x8*)&Ks[j * 64 + (((ks * 4 + kq) ^ (j & 7)) << 3)];
      }
#pragma unroll
      for (int it = 0; it < 4; it++)
#pragma unroll
        for (int jt = 0; jt < 2; jt++) {
          f32x4 s = (f32x4){0.f, 0.f, 0.f, 0.f};
          s = MFMA16(qf[it][0], kf[jt][0], s);
          s = MFMA16(qf[it][1], kf[jt][1], s);
#pragma unroll
          for (int r = 0; r < 4; r++) {
            float p = __expf(s[r] * 0.125f);
            rsum[it][r] += p;
            Ps[(it * 16 + kq * 4 + r) * 40 + jt * 16 + m16] = __float2bfloat16(p);
          }
        }
      bf16x8 pf[4], vf[4];
#pragma unroll
      for (int it = 0; it < 4; it++)
        pf[it] = *(const bf16x8*)&Ps[(it * 16 + m16) * 40 + kq * 8];
#pragma unroll
      for (int dt = 0; dt < 4; dt++)
        vf[dt] = *(const bf16x8*)&Vt[(dt * 16 + m16) * 128 +
                                     (((jcl * 4 + kq) ^ (m16 & 7)) << 3)];
#pragma unroll
      for (int it = 0; it < 4; it++)
#pragma unroll
        for (int dt = 0; dt < 4; dt++) acc[it][dt] = MFMA16(pf[it], vf[dt], acc[it][dt]);
    }
  }

#pragma unroll
  for (int it = 0; it < 4; it++)
#pragma unroll
    for (int r = 0; r < 4; r++) {
      float s = rsum[it][r];
      s += __shfl_xor(s, 1); s += __shfl_xor(s, 2);
      s += __shfl_xor(s, 4); s += __shfl_xor(s, 8);
      rsum[it][r] = 1.f / s;
    }
#pragma unroll
  for (int it = 0; it < 4; it++)
#pragma unroll
    for (int dt = 0; dt < 4; dt++)
#pragma unroll
      for (int r = 0; r < 4; r++) {
        const int i = i0 + it * 16 + kq * 4 + r;  // = h
        Ow[((size_t)(w * 256 + i)) * 512 + head * 64 + dt * 16 + m16] =
            __float2bfloat16(acc[it][dt][r] * rsum[it][r]);
      }
}

// ---------------------------------------------------------------- FUSED height tied dots (split-K)
// R7-proven 2-barrier form, loads pre-cast bf16 xh (deletes cvt8, halves read bytes).
// grid (16 tiles 64x64, 8 heads, 8 rc), block 256 = 4 waves.
__global__ void __launch_bounds__(256, 2)
k_dots_f(const bf16* __restrict__ xh, const bf16* __restrict__ Wt, float* __restrict__ dp) {
  __shared__ __align__(16) bf16 Qs[64 * 72];
  __shared__ __align__(16) bf16 Ks[64 * 72];
  const int tile = blockIdx.x, head = blockIdx.y, rc = blockIdx.z;
  const int i0 = (tile >> 2) * 64, j0 = (tile & 3) * 64;
  const int tid = threadIdx.x, lane = tid & 63, wv = tid >> 6;
  const int m16 = lane & 15, kq = lane >> 4;
  float* slice = dp + (size_t)rc * 524288 + (size_t)head * 65536;

  const bf16* WtQ = Wt + (size_t)(head * 64) * 64 + kq * 8;
  const bf16* WtK = Wt + (size_t)(512 + head * 64) * 64 + kq * 8;

  f32x4 acc[4];
#pragma unroll
  for (int b = 0; b < 4; b++) acc[b] = (f32x4){0.f, 0.f, 0.f, 0.f};

  const int lrow = wv * 16 + kq * 4;

#pragma unroll 1
  for (int rr = 0; rr < 32; rr++) {
    const int rbase = (rc * 32 + rr) * 256;
    __syncthreads();  // prior iteration's dots reads done
    {
      const bf16* xr = xh + (size_t)(rbase + i0 + wv * 16 + m16) * 64 + kq * 8;
      const bf16x8 qa0 = *(const bf16x8*)xr;
      const bf16x8 qa1 = *(const bf16x8*)(xr + 32);
      const bf16* yr = xh + (size_t)(rbase + j0 + wv * 16 + m16) * 64 + kq * 8;
      const bf16x8 ka0 = *(const bf16x8*)yr;
      const bf16x8 ka1 = *(const bf16x8*)(yr + 32);
#pragma unroll
      for (int nt = 0; nt < 4; nt++) {
        const bf16* wq = WtQ + (size_t)(nt * 16 + m16) * 64;
        f32x4 aq = (f32x4){0.f, 0.f, 0.f, 0.f};
        aq = MFMA16(qa0, *(const bf16x8*)wq, aq);
        aq = MFMA16(qa1, *(const bf16x8*)(wq + 32), aq);
        const bf16* wk = WtK + (size_t)(nt * 16 + m16) * 64;
        f32x4 ak = (f32x4){0.f, 0.f, 0.f, 0.f};
        ak = MFMA16(ka0, *(const bf16x8*)wk, ak);
        ak = MFMA16(ka1, *(const bf16x8*)(wk + 32), ak);
#pragma unroll
        for (int r = 0; r < 4; r++) {
          Qs[(lrow + r) * 72 + nt * 16 + m16] = __float2bfloat16(aq[r]);
          Ks[(lrow + r) * 72 + nt * 16 + m16] = __float2bfloat16(ak[r]);
        }
      }
    }
    __syncthreads();
#pragma unroll
    for (int ks = 0; ks < 2; ks++) {
      bf16x8 af = *(const bf16x8*)&Qs[(wv * 16 + m16) * 72 + ks * 32 + kq * 8];
      bf16x8 bfr[4];
#pragma unroll
      for (int jt = 0; jt < 4; jt++)
        bfr[jt] = *(const bf16x8*)&Ks[(jt * 16 + m16) * 72 + ks * 32 + kq * 8];
#pragma unroll
      for (int jt = 0; jt < 4; jt++) acc[jt] = MFMA16(af, bfr[jt], acc[jt]);
    }
  }
  const float sc = 1.f / 128.f;  // dh^-0.5 * H^-0.5
#pragma unroll
  for (int jt = 0; jt < 4; jt++)
#pragma unroll
    for (int r = 0; r < 4; r++)
      slice[(size_t)(i0 + wv * 16 + kq * 4 + r) * 256 + j0 + jt * 16 + m16] = acc[jt][r] * sc;
}

// ---------------------------------------------------------------- pair bias: LN + @W_pair -> dp slice 0
__global__ void __launch_bounds__(256) k_pb(const float* __restrict__ pb,
                                            const float* __restrict__ g,
                                            const float* __restrict__ bb,
                                            const float* __restrict__ Wp,
                                            float* __restrict__ dots) {
  __shared__ float sn[4][128];
  const int tid = threadIdx.x, lane = tid & 63, wv = tid >> 6;
  const size_t ij = (size_t)blockIdx.x * 4 + wv;
  const float2 xv = *(const float2*)(pb + ij * 128 + lane * 2);

  float s = xv.x + xv.y;
#pragma unroll
  for (int o = 1; o < 64; o <<= 1) s += __shfl_xor(s, o);
  const float mu = s * (1.f / 128.f);
  const float d0 = xv.x - mu, d1 = xv.y - mu;
  float s2 = d0 * d0 + d1 * d1;
#pragma unroll
  for (int o = 1; o < 64; o <<= 1) s2 += __shfl_xor(s2, o);
  const float inv = rsqrtf(s2 * (1.f / 128.f) + 1e-5f);

  sn[wv][lane * 2 + 0] = d0 * inv * g[lane * 2 + 0] + bb[lane * 2 + 0];
  sn[wv][lane * 2 + 1] = d1 * inv * g[lane * 2 + 1] + bb[lane * 2 + 1];

  const int h = lane & 7, gp = lane >> 3;
  float a = 0.f;
#pragma unroll
  for (int p0 = 0; p0 < 16; p0++) {
    const int p = gp * 16 + p0;
    a += sn[wv][p] * Wp[p * 8 + h];
  }
  a += __shfl_xor(a, 8);
  a += __shfl_xor(a, 16);
  a += __shfl_xor(a, 32);
  if (lane < 8) dots[(size_t)h * 65536 + ij] += a;
}

// ---------------------------------------------------------------- softmax summing 8 split-K slices -> bf16 P
__global__ void __launch_bounds__(256) k_softmax8(const float* __restrict__ dp,
                                                  bf16* __restrict__ P) {
  __shared__ float red[4];
  const int i = blockIdx.x, head = blockIdx.y, t = threadIdx.x;
  const size_t base = (size_t)head * 65536 + i * 256 + t;
  float lg = 0.f;
#pragma unroll
  for (int s = 0; s < 8; s++) lg += dp[(size_t)s * 524288 + base];
  const float e = __expf(lg);
  float s = e;
#pragma unroll
  for (int o = 1; o < 64; o <<= 1) s += __shfl_xor(s, o);
  if ((t & 63) == 0) red[t >> 6] = s;
  __syncthreads();
  const float S = red[0] + red[1] + red[2] + red[3];
  P[base] = __float2bfloat16(e / S);
}

// ---------------------------------------------------------------- FUSED height PV -> Oh (h-major)
// V projected on the fly from bf16 xh; MFMA C-layout (col=d, row=j) writes the
// transposed swizzled Vt directly (free transpose).
__global__ void __launch_bounds__(256, 2)
k_h_pv_f(const bf16* __restrict__ P, const bf16* __restrict__ xh,
         const bf16* __restrict__ Wt, bf16* __restrict__ Oh) {
  __shared__ __align__(16) bf16 Vt[64 * 256];
  const int r = blockIdx.x, head = blockIdx.y;
  const int tid = threadIdx.x, lane = tid & 63, wv = tid >> 6;
  const int m16 = lane & 15, kq = lane >> 4;

  {  // V projection: this wave computes j rows wv*64 .. +64 (xh rows r*256 + j)
    const bf16* WtV = Wt + (size_t)(1024 + head * 64) * 64 + kq * 8;
#pragma unroll
    for (int mt = 0; mt < 4; mt++) {
      const int jb16 = wv * 64 + mt * 16;
      const bf16* xr = xh + (size_t)(r * 256 + jb16 + m16) * 64 + kq * 8;
      const bf16x8 a0 = *(const bf16x8*)xr;
      const bf16x8 a1 = *(const bf16x8*)(xr + 32);
#pragma unroll
      for (int nt = 0; nt < 4; nt++) {
        const int d = nt * 16 + m16;
        const bf16* wp = WtV + (size_t)(nt * 16 + m16) * 64;
        f32x4 a = (f32x4){0.f, 0.f, 0.f, 0.f};
        a = MFMA16(a0, *(const bf16x8*)wp, a);
        a = MFMA16(a1, *(const bf16x8*)(wp + 32), a);
        const int j = jb16 + kq * 4;  // 4 consecutive j (r2=0..3), same 8-granule
        bf16 tmp[4];
#pragma unroll
        for (int r2 = 0; r2 < 4; r2++) tmp[r2] = __float2bfloat16(a[r2]);
        *(uint2*)&Vt[d * 256 + (((j >> 3) ^ (d & 7)) << 3) + (j & 7)] = *(const uint2*)tmp;
      }
    }
  }

  const bf16* Pb = P + (size_t)head * 65536;
  const int i0 = wv * 64;
  auto loadP = [&](int ks, bf16x8 pf[4]) {
#pragma unroll
    for (int it = 0; it < 4; it++)
      pf[it] = *(const bf16x8*)(Pb + (size_t)(i0 + it * 16 + m16) * 256 + ks * 32 + kq * 8);
  };
  bf16x8 pcur[4];
  loadP(0, pcur);
  __syncthreads();

  f32x4 acc[4][4];
#pragma unroll
  for (int a = 0; a < 4; a++)
#pragma unroll
    for (int b = 0; b < 4; b++) acc[a][b] = (f32x4){0.f, 0.f, 0.f, 0.f};

#pragma unroll 1
  for (int ks = 0; ks < 8; ks++) {
    bf16x8 pnext[4];
    if (ks < 7) loadP(ks + 1, pnext);
    bf16x8 vf[4];
#pragma unroll
    for (int dt = 0; dt < 4; dt++)
      vf[dt] = *(const bf16x8*)&Vt[(dt * 16 + m16) * 256 + (((ks * 4 + kq) ^ (m16 & 7)) << 3)];
#pragma unroll
    for (int it = 0; it < 4; it++)
#pragma unroll
      for (int dt = 0; dt < 4; dt++) acc[it][dt] = MFMA16(pcur[it], vf[dt], acc[it][dt]);
    if (ks < 7) {
#pragma unroll
      for (int it = 0; it < 4; it++) pcur[it] = pnext[it];
    }
  }
#pragma unroll
  for (int it = 0; it < 4; it++)
#pragma unroll
    for (int dt = 0; dt < 4; dt++)
#pragma unroll
      for (int r2 = 0; r2 < 4; r2++) {
        const int i = i0 + it * 16 + kq * 4 + r2;  // w position
        Oh[((size_t)(r * 256 + i)) * 512 + head * 64 + dt * 16 + m16] =
            __float2bfloat16(acc[it][dt][r2]);
      }
}

// ---------------------------------------------------------------- final fused projection
// out[n] = 0.5*(Ow@Wout_w + Oh@Wout_h)[n] + 0.5*(bw+bh); n = h*256+w (h-major).
// Ow is w-major: its row for out-row n is ((n&255)<<8)|(n>>8).
__global__ void __launch_bounds__(256) k_outproj(const bf16* __restrict__ Ow,
                                                 const bf16* __restrict__ Oh,
                                                 const bf16* __restrict__ Wow,  // [64][512]
                                                 const bf16* __restrict__ Woh,
                                                 const float* __restrict__ bw,
                                                 const float* __restrict__ bh,
                                                 float* __restrict__ out) {
  const int tid = threadIdx.x, lane = tid & 63, wv = tid >> 6;
  const int m16 = lane & 15, kq = lane >> 4;
  const int nA = blockIdx.x * 64 + wv * 16 + m16;
  const int wA = ((nA & 255) << 8) | (nA >> 8);  // w-major remap for Ow

  const bf16* aw = Ow + (size_t)wA * 512 + kq * 8;
  const bf16* ah = Oh + (size_t)nA * 512 + kq * 8;

  f32x4 acc[4];
#pragma unroll
  for (int ct = 0; ct < 4; ct++) acc[ct] = (f32x4){0.f, 0.f, 0.f, 0.f};

#pragma unroll 1
  for (int kc = 0; kc < 16; kc++) {
    const bf16x8 afw = *(const bf16x8*)(aw + kc * 32);
    const bf16x8 afh = *(const bf16x8*)(ah + kc * 32);
#pragma unroll
    for (int ct = 0; ct < 4; ct++) {
      const bf16x8 bfw = *(const bf16x8*)(Wow + (size_t)(ct * 16 + m16) * 512 + kc * 32 + kq * 8);
      const bf16x8 bfh = *(const bf16x8*)(Woh + (size_t)(ct * 16 + m16) * 512 + kc * 32 + kq * 8);
      acc[ct] = MFMA16(afw, bfw, acc[ct]);
      acc[ct] = MFMA16(afh, bfh, acc[ct]);
    }
  }
  const int n0 = blockIdx.x * 64 + wv * 16 + kq * 4;
#pragma unroll
  for (int ct = 0; ct < 4; ct++) {
    const int c = ct * 16 + m16;
    const float bias = 0.5f * (bw[c] + bh[c]);
#pragma unroll
    for (int r = 0; r < 4; r++)
      out[(size_t)(n0 + r) * 64 + c] = 0.5f * acc[ct][r] + bias;
  }
}

// ================================================================ launch
extern "C" void kernel_launch(void* const* d_in, const int* in_sizes, int n_in,
                              void* d_out, int out_size, void* d_ws, size_t ws_size,
                              hipStream_t stream) {
  const float* x      = (const float*)d_in[0];
  const float* pair   = (const float*)d_in[1];
  const float* Wq_w   = (const float*)d_in[2];
  const float* Wkv_w  = (const float*)d_in[3];
  const float* Wout_w = (const float*)d_in[4];
  const float* bout_w = (const float*)d_in[5];
  const float* Wq_h   = (const float*)d_in[6];
  const float* Wkv_h  = (const float*)d_in[7];
  const float* Wout_h = (const float*)d_in[8];
  const float* bout_h = (const float*)d_in[9];
  const float* ln_g   = (const float*)d_in[10];
  const float* ln_b   = (const float*)d_in[11];
  const float* W_pair = (const float*)d_in[12];
  float* out = (float*)d_out;

  char* ws = (char*)d_ws;
  bf16* R0 = (bf16*)ws;                     // width Ow (w-major)
  bf16* xh = (bf16*)(ws + 67108864);        // 8MB bf16 x, h-major
  bf16* xw = (bf16*)(ws + 67108864 + 8388608);  // 8MB bf16 x, w-major
  bf16* R2 = (bf16*)(ws + 134217728);       // Oh (h-major)
  bf16* Wt_w = (bf16*)(ws + 201326592);           // 384K
  bf16* Wt_h = (bf16*)(ws + 201326592 + 393216);  // 384K
  bf16* P  = (bf16*)(ws + 201326592 + 786432);    // 1M
  bf16* Wo_w = (bf16*)(ws + 201326592 + 1835008); // 64K
  bf16* Wo_h = Wo_w + 32768;                      // 64K
  float* dp = out;                          // d_out doubles as split-K scratch (16MB exact)

  // -------- input cast + weight prep (up front) --------
  k_xT2<<<4096, 256, 0, stream>>>(x, xh, xw);   // 4,194,304 floats / (256*4)
  k_wt2<<<768, 256, 0, stream>>>(Wq_w, Wkv_w, Wq_h, Wkv_h, Wt_w, Wt_h);
  k_wo<<<256, 256, 0, stream>>>(Wout_w, Wout_h, Wo_w, Wo_h);

  // -------- width attention phase (fully fused QKV + attention) --------
  k_width_fused<<<dim3(WW, NHEADS), 256, 0, stream>>>(xw, Wt_w, R0);

  // -------- height attention phase (fully fused projections) --------
  k_dots_f<<<dim3(16, NHEADS, 8), 256, 0, stream>>>(xh, Wt_h, dp);
  k_pb<<<65536 / 4, 256, 0, stream>>>(pair, ln_g, ln_b, W_pair, dp);  // into slice 0
  k_softmax8<<<dim3(256, NHEADS), 256, 0, stream>>>(dp, P);
  k_h_pv_f<<<dim3(HH, NHEADS), 256, 0, stream>>>(P, xh, Wt_h, R2);    // Oh

  // -------- final fused projection (sole writer of out) --------
  k_outproj<<<1024, 256, 0, stream>>>(R0, R2, Wo_w, Wo_h, bout_w, bout_h, out);
}